// Round 2
// baseline (457.716 us; speedup 1.0000x reference)
//
#include <hip/hip_runtime.h>
#include <hip/hip_bf16.h>

// Problem constants (from setup_inputs)
#define NROWS 131072
#define DIN   512
#define HDIM  128
#define EDIM  32
#define KCODES 512

typedef unsigned short ushort_t;
typedef unsigned int   uint_t;

// ---------- bf16 helpers (manual, RNE pack) ----------
__device__ __forceinline__ float bflo(uint_t u) {
  union { uint_t u; float f; } x; x.u = u << 16; return x.f;
}
__device__ __forceinline__ float bfhi(uint_t u) {
  union { uint_t u; float f; } x; x.u = u & 0xffff0000u; return x.f;
}
__device__ __forceinline__ float bfu(ushort_t u) {
  union { uint_t u; float f; } x; x.u = ((uint_t)u) << 16; return x.f;
}
__device__ __forceinline__ ushort_t f2bf(float f) {
  union { float f; uint_t u; } x; x.f = f;
  uint_t u = x.u;
  return (ushort_t)((u + 0x7fffu + ((u >> 16) & 1u)) >> 16);
}

// ---------------------------------------------------------------------------
// K1: H1 = X @ W1 + b1  (fp32 VALU GEMM, 128-row tile), H1 stored bf16.
// Also accumulates per-column sum / sumsq for BN stats.
// grid 1024 x 256
// ---------------------------------------------------------------------------
__global__ __launch_bounds__(256, 2) void k_gemm1(
    const float* __restrict__ X, const float* __restrict__ W1,
    const float* __restrict__ b1, ushort_t* __restrict__ H1,
    float* __restrict__ colsum, float* __restrict__ colsumsq)
{
  __shared__ float Xs[32 * 132];   // [k][row], stride 132 (pad: align + banks)
  __shared__ float W1s[32 * 132];  // [k][col], stride 132
  __shared__ float lsum[128];
  __shared__ float lssq[128];
  const int tid = threadIdx.x;
  const int row0 = blockIdx.x * 128;
  if (tid < 128) { lsum[tid] = 0.f; lssq[tid] = 0.f; }
  const int ty = tid >> 4;   // 0..15 -> rows ty*8..+7
  const int tx = tid & 15;   // cols tx*4+j and 64+tx*4+j

  float acc[8][8];
#pragma unroll
  for (int i = 0; i < 8; ++i)
#pragma unroll
    for (int j = 0; j < 8; ++j) acc[i][j] = 0.f;

  const int lr = tid >> 3;        // X stage: row base 0..31
  const int lk = (tid & 7) * 4;   // X stage: k quad
  const int wk = tid >> 5;        // W1 stage: k base 0..7
  const int wc = (tid & 31) * 4;  // W1 stage: col quad

  for (int kc = 0; kc < DIN; kc += 32) {
#pragma unroll
    for (int it = 0; it < 4; ++it) {
      int r = lr + it * 32;
      float4 v = *(const float4*)(X + (size_t)(row0 + r) * DIN + kc + lk);
      Xs[(lk + 0) * 132 + r] = v.x;
      Xs[(lk + 1) * 132 + r] = v.y;
      Xs[(lk + 2) * 132 + r] = v.z;
      Xs[(lk + 3) * 132 + r] = v.w;
    }
#pragma unroll
    for (int it = 0; it < 4; ++it) {
      int kk = wk + it * 8;
      float4 v = *(const float4*)(W1 + (size_t)(kc + kk) * HDIM + wc);
      *(float4*)(W1s + kk * 132 + wc) = v;
    }
    __syncthreads();
#pragma unroll 8
    for (int kk = 0; kk < 32; ++kk) {
      float4 a0 = *(const float4*)(Xs + kk * 132 + ty * 8);
      float4 a1 = *(const float4*)(Xs + kk * 132 + ty * 8 + 4);
      float4 w0 = *(const float4*)(W1s + kk * 132 + tx * 4);
      float4 w1 = *(const float4*)(W1s + kk * 132 + 64 + tx * 4);
      float a[8] = {a0.x, a0.y, a0.z, a0.w, a1.x, a1.y, a1.z, a1.w};
      float w[8] = {w0.x, w0.y, w0.z, w0.w, w1.x, w1.y, w1.z, w1.w};
#pragma unroll
      for (int i = 0; i < 8; ++i)
#pragma unroll
        for (int j = 0; j < 8; ++j) acc[i][j] += a[i] * w[j];
    }
    __syncthreads();
  }

  // epilogue: +bias, write bf16 H1, accumulate stats
  float bcol[8];
#pragma unroll
  for (int j = 0; j < 8; ++j)
    bcol[j] = b1[(j < 4) ? (tx * 4 + j) : (64 + tx * 4 + j - 4)];
  float s[8], ss[8];
#pragma unroll
  for (int j = 0; j < 8; ++j) { s[j] = 0.f; ss[j] = 0.f; }
#pragma unroll
  for (int i = 0; i < 8; ++i) {
    float h[8];
#pragma unroll
    for (int j = 0; j < 8; ++j) {
      h[j] = acc[i][j] + bcol[j];
      s[j] += h[j]; ss[j] += h[j] * h[j];
    }
    int r = row0 + ty * 8 + i;
    uint2 p0, p1;
    p0.x = (uint_t)f2bf(h[0]) | ((uint_t)f2bf(h[1]) << 16);
    p0.y = (uint_t)f2bf(h[2]) | ((uint_t)f2bf(h[3]) << 16);
    p1.x = (uint_t)f2bf(h[4]) | ((uint_t)f2bf(h[5]) << 16);
    p1.y = (uint_t)f2bf(h[6]) | ((uint_t)f2bf(h[7]) << 16);
    *(uint2*)(H1 + (size_t)r * HDIM + tx * 4) = p0;
    *(uint2*)(H1 + (size_t)r * HDIM + 64 + tx * 4) = p1;
  }
#pragma unroll
  for (int j = 0; j < 8; ++j) {
    int c = (j < 4) ? (tx * 4 + j) : (64 + tx * 4 + j - 4);
    atomicAdd(&lsum[c], s[j]);
    atomicAdd(&lssq[c], ss[j]);
  }
  __syncthreads();
  if (tid < 128) {
    atomicAdd(&colsum[tid], lsum[tid]);
    atomicAdd(&colsumsq[tid], lssq[tid]);
  }
}

// ---------------------------------------------------------------------------
// BN params for encoder: scale1 = g*rsqrt(var+eps), shift1 = be - mu*scale1
// ---------------------------------------------------------------------------
__global__ void k_bn1(const float* __restrict__ colsum,
                      const float* __restrict__ colsumsq,
                      const float* __restrict__ g, const float* __restrict__ be,
                      float* __restrict__ scale, float* __restrict__ shift)
{
  int j = threadIdx.x;
  float mu = colsum[j] * (1.f / NROWS);
  float var = colsumsq[j] * (1.f / NROWS) - mu * mu;
  float sc = g[j] * rsqrtf(var + 1e-5f);
  scale[j] = sc;
  shift[j] = be[j] - mu * sc;
}

// codebook row norms
__global__ void k_cn(const float* __restrict__ CB, float* __restrict__ cn)
{
  int k = threadIdx.x;  // 512
  float s = 0.f;
#pragma unroll
  for (int e = 0; e < EDIM; ++e) { float c = CB[k * EDIM + e]; s += c * c; }
  cn[k] = s;
}

// ---------------------------------------------------------------------------
// K3: fused BN+ReLU -> Z = Hb@W2+b2 -> nearest-code argmin.
// 64 rows/block, grid 2048 x 256.
// Outputs: topics[n], global counts histogram, Zloss (sum of min dists).
// ---------------------------------------------------------------------------
__global__ __launch_bounds__(256, 2) void k_encode(
    const ushort_t* __restrict__ H1, const float* __restrict__ scale1,
    const float* __restrict__ shift1, const float* __restrict__ W2,
    const float* __restrict__ b2, const float* __restrict__ CB,
    const float* __restrict__ cn, int* __restrict__ topics,
    int* __restrict__ counts, float* __restrict__ Zloss)
{
  __shared__ ushort_t Hb[64 * 136];    // bf16 activations, stride 136 (16B align + banks)
  __shared__ ushort_t cbl[512 * 36];   // bf16 codebook, stride 36
  __shared__ float Zt[64 * 33];        // fp32 Z tile, stride 33
  __shared__ int hist[512];
  __shared__ float zsh;

  const int tid = threadIdx.x;
  const int row0 = blockIdx.x * 64;

  hist[tid] = 0; hist[tid + 256] = 0;
  if (tid == 0) zsh = 0.f;

  // ---- phase 0a: stage H1 tile with BN+ReLU applied ----
  {
    const int r0 = tid >> 4;          // 0..15
    const int c0 = (tid * 8) & 127;   // multiple of 8
    float sc[8], sh[8];
    {
      float4 a = *(const float4*)(scale1 + c0);
      float4 b = *(const float4*)(scale1 + c0 + 4);
      sc[0]=a.x; sc[1]=a.y; sc[2]=a.z; sc[3]=a.w; sc[4]=b.x; sc[5]=b.y; sc[6]=b.z; sc[7]=b.w;
      float4 e = *(const float4*)(shift1 + c0);
      float4 f = *(const float4*)(shift1 + c0 + 4);
      sh[0]=e.x; sh[1]=e.y; sh[2]=e.z; sh[3]=e.w; sh[4]=f.x; sh[5]=f.y; sh[6]=f.z; sh[7]=f.w;
    }
#pragma unroll
    for (int it = 0; it < 4; ++it) {
      int r = r0 + it * 16;
      uint4 v = *(const uint4*)(H1 + (size_t)(row0 + r) * HDIM + c0);
      uint_t u[4] = {v.x, v.y, v.z, v.w};
      uint_t o[4];
#pragma unroll
      for (int m = 0; m < 4; ++m) {
        float f0 = fmaxf(bflo(u[m]) * sc[2*m]   + sh[2*m],   0.f);
        float f1 = fmaxf(bfhi(u[m]) * sc[2*m+1] + sh[2*m+1], 0.f);
        o[m] = (uint_t)f2bf(f0) | ((uint_t)f2bf(f1) << 16);
      }
      *(uint4*)(Hb + r * 136 + c0) = make_uint4(o[0], o[1], o[2], o[3]);
    }
  }
  // ---- phase 0b: stage codebook as bf16 ----
  {
#pragma unroll
    for (int it = 0; it < 16; ++it) {
      int f = tid + it * 256;   // float4 index
      int c = f >> 3;
      int e4 = (f & 7) * 4;
      float4 v = *(const float4*)(CB + (size_t)c * EDIM + e4);
      ushort_t* p = cbl + c * 36 + e4;
      p[0] = f2bf(v.x); p[1] = f2bf(v.y); p[2] = f2bf(v.z); p[3] = f2bf(v.w);
    }
  }
  __syncthreads();

  // ---- phase 1: Z = Hb @ W2 + b2 (2 rows x 4 cols per thread) ----
  {
    const int rowg = tid >> 3;   // 0..31 -> rows rowg*2, rowg*2+1
    const int colg = tid & 7;    // cols colg*4..+3
    const int hb0 = (rowg * 2) * 136;
    const int hb1 = hb0 + 136;
    float za00=0,za01=0,za02=0,za03=0, za10=0,za11=0,za12=0,za13=0;
#pragma unroll 4
    for (int k = 0; k < HDIM; ++k) {
      float h0 = bfu(Hb[hb0 + k]);
      float h1 = bfu(Hb[hb1 + k]);
      float4 w = *(const float4*)(W2 + k * EDIM + colg * 4);
      za00 += h0 * w.x; za01 += h0 * w.y; za02 += h0 * w.z; za03 += h0 * w.w;
      za10 += h1 * w.x; za11 += h1 * w.y; za12 += h1 * w.z; za13 += h1 * w.w;
    }
    float4 bb = *(const float4*)(b2 + colg * 4);
    int zb = (rowg * 2) * 33 + colg * 4;
    Zt[zb + 0] = za00 + bb.x; Zt[zb + 1] = za01 + bb.y;
    Zt[zb + 2] = za02 + bb.z; Zt[zb + 3] = za03 + bb.w;
    Zt[zb + 33 + 0] = za10 + bb.x; Zt[zb + 33 + 1] = za11 + bb.y;
    Zt[zb + 33 + 2] = za12 + bb.z; Zt[zb + 33 + 3] = za13 + bb.w;
  }
  __syncthreads();

  // ---- phase 2: distances + argmin. thread = (row rp & rp+32, code class q) ----
  {
    const int rp = tid >> 3;  // 0..31
    const int q = tid & 7;    // codes c = i*8+q
    float z0[32], z1[32];
    float zn0 = 0.f, zn1 = 0.f;
#pragma unroll
    for (int e = 0; e < 32; ++e) {
      z0[e] = Zt[rp * 33 + e];        zn0 += z0[e] * z0[e];
      z1[e] = Zt[(rp + 32) * 33 + e]; zn1 += z1[e] * z1[e];
    }
    float minv0 = 3.4e38f, minv1 = 3.4e38f;
    int mini0 = 0, mini1 = 0;
    for (int i = 0; i < 64; ++i) {
      const int c = i * 8 + q;
      const ushort_t* cp = cbl + c * 36;
      float d0a = 0.f, d0b = 0.f, d1a = 0.f, d1b = 0.f;
#pragma unroll
      for (int e4 = 0; e4 < 8; e4 += 2) {
        uint2 wa = *(const uint2*)(cp + e4 * 4);
        uint2 wb = *(const uint2*)(cp + e4 * 4 + 4);
        float w0 = bflo(wa.x), w1 = bfhi(wa.x), w2 = bflo(wa.y), w3 = bfhi(wa.y);
        float w4 = bflo(wb.x), w5 = bfhi(wb.x), w6 = bflo(wb.y), w7 = bfhi(wb.y);
        const int e = e4 * 4;
        d0a += z0[e+0]*w0 + z0[e+1]*w1 + z0[e+2]*w2 + z0[e+3]*w3;
        d0b += z0[e+4]*w4 + z0[e+5]*w5 + z0[e+6]*w6 + z0[e+7]*w7;
        d1a += z1[e+0]*w0 + z1[e+1]*w1 + z1[e+2]*w2 + z1[e+3]*w3;
        d1b += z1[e+4]*w4 + z1[e+5]*w5 + z1[e+6]*w6 + z1[e+7]*w7;
      }
      float cc = cn[c];
      float d0 = cc - 2.f * (d0a + d0b);
      float d1 = cc - 2.f * (d1a + d1b);
      if (d0 < minv0) { minv0 = d0; mini0 = c; }
      if (d1 < minv1) { minv1 = d1; mini1 = c; }
    }
    // reduce across the 8 code-classes (adjacent lanes), first-min tie-break
#pragma unroll
    for (int m = 1; m < 8; m <<= 1) {
      float ov = __shfl_xor(minv0, m, 64); int oi = __shfl_xor(mini0, m, 64);
      if (ov < minv0 || (ov == minv0 && oi < mini0)) { minv0 = ov; mini0 = oi; }
      ov = __shfl_xor(minv1, m, 64); oi = __shfl_xor(mini1, m, 64);
      if (ov < minv1 || (ov == minv1 && oi < mini1)) { minv1 = ov; mini1 = oi; }
    }
    if (q == 0) {
      topics[row0 + rp] = mini0;
      topics[row0 + rp + 32] = mini1;
      atomicAdd(&hist[mini0], 1);
      atomicAdd(&hist[mini1], 1);
      atomicAdd(&zsh, (minv0 + zn0) + (minv1 + zn1));
    }
  }
  __syncthreads();
  {
    int h0 = hist[tid], h1 = hist[tid + 256];
    if (h0) atomicAdd(&counts[tid], h0);
    if (h1) atomicAdd(&counts[tid + 256], h1);
    if (tid == 0) atomicAdd(Zloss, zsh);
  }
}

// ---------------------------------------------------------------------------
// Decoder table T = codebook @ dec_W1 + dec_b1   [512 x 128]
// ---------------------------------------------------------------------------
__global__ __launch_bounds__(256) void k_T(const float* __restrict__ CB,
    const float* __restrict__ dW1, const float* __restrict__ db1,
    float* __restrict__ T)
{
  int gid = blockIdx.x * 256 + threadIdx.x;  // 0..65535
  int k = gid >> 7, j = gid & 127;
  float acc = db1[j];
#pragma unroll
  for (int e = 0; e < EDIM; ++e) acc += CB[k * EDIM + e] * dW1[e * HDIM + j];
  T[gid] = acc;
}

// Decoder BN params from topic histogram (exact batch stats)
__global__ void k_bn2(const int* __restrict__ counts, const float* __restrict__ T,
    const float* __restrict__ g, const float* __restrict__ be,
    float* __restrict__ scale2, float* __restrict__ shift2)
{
  __shared__ float cw[512];
  int j = threadIdx.x;  // 128
  for (int i = j; i < 512; i += 128) cw[i] = (float)counts[i];
  __syncthreads();
  float s = 0.f, ss = 0.f;
  for (int k = 0; k < KCODES; ++k) {
    float t = T[k * HDIM + j];
    float c = cw[k];
    s += c * t; ss += c * t * t;
  }
  float mu = s * (1.f / NROWS);
  float var = ss * (1.f / NROWS) - mu * mu;
  float sc = g[j] * rsqrtf(var + 1e-5f);
  scale2[j] = sc;
  shift2[j] = be[j] - mu * sc;
}

// U = relu(bn(T)) @ dec_W2 + dec_b2   [512 x 512]; block = half a row of U
__global__ __launch_bounds__(256) void k_U(const float* __restrict__ T,
    const float* __restrict__ scale2, const float* __restrict__ shift2,
    const float* __restrict__ dW2, const float* __restrict__ db2,
    float* __restrict__ U)
{
  __shared__ float Tb[128];
  const int tid = threadIdx.x;
  const int k = blockIdx.x >> 1;
  const int c = (blockIdx.x & 1) * 256 + tid;
  if (tid < 128) Tb[tid] = fmaxf(T[k * HDIM + tid] * scale2[tid] + shift2[tid], 0.f);
  __syncthreads();
  float acc = db2[c];
#pragma unroll 8
  for (int j = 0; j < HDIM; ++j) acc += Tb[j] * dW2[j * 512 + c];
  U[(size_t)k * 512 + c] = acc;
}

// Reconstruction: R += sum_n ||U[topic[n]] - X[n]||^2  (one row per wave-iter)
__global__ __launch_bounds__(256, 4) void k_recon(
    const float* __restrict__ X, const float* __restrict__ U,
    const int* __restrict__ topics, float* __restrict__ Rsum)
{
  __shared__ float bsum;
  const int tid = threadIdx.x;
  if (tid == 0) bsum = 0.f;
  __syncthreads();
  const int lane = tid & 63;
  const int wave = blockIdx.x * 4 + (tid >> 6);
  float acc = 0.f;
  for (int r = wave; r < NROWS; r += 4096) {
    const int t = topics[r];
    const float4* xr = (const float4*)(X + (size_t)r * DIN);
    const float4* ur = (const float4*)(U + (size_t)t * 512);
    float4 x0 = xr[lane],     u0 = ur[lane];
    float4 x1 = xr[lane + 64], u1 = ur[lane + 64];
    float d;
    d = x0.x - u0.x; acc += d * d;
    d = x0.y - u0.y; acc += d * d;
    d = x0.z - u0.z; acc += d * d;
    d = x0.w - u0.w; acc += d * d;
    d = x1.x - u1.x; acc += d * d;
    d = x1.y - u1.y; acc += d * d;
    d = x1.z - u1.z; acc += d * d;
    d = x1.w - u1.w; acc += d * d;
  }
#pragma unroll
  for (int off = 32; off > 0; off >>= 1) acc += __shfl_down(acc, off, 64);
  if (lane == 0) atomicAdd(&bsum, acc);
  __syncthreads();
  if (tid == 0) atomicAdd(Rsum, bsum);
}

__global__ void k_final(const float* __restrict__ Zloss,
                        const float* __restrict__ Rsum, float* __restrict__ out)
{
  // C_loss == Z_loss in forward (stop_gradient is identity forward)
  out[0] = 2.f * Zloss[0] + sqrtf(Rsum[0]);
}

// ---------------------------------------------------------------------------
// Workspace layout (bytes):                              total ~35.4 MB
//   0         H1 bf16            [N*128]      33,554,432
//   33554432  topics int32       [N]             524,288
//   34078720  accumulators (memset 0 each launch):
//               colsum[128] f32 @ +0
//               colsumsq[128]   @ +512
//               counts[512] i32 @ +1024
//               Zloss f32       @ +3072
//               Rsum  f32       @ +3076        (block = 4096)
//   34082816  scale1[128]+shift1[128]            1,024
//   34083840  cn[512]                            2,048
//   34085888  T[512*128]                       262,144
//   34348032  scale2[128]+shift2[128]            1,024
//   34349056  U[512*512]                     1,048,576
// ---------------------------------------------------------------------------
extern "C" void kernel_launch(void* const* d_in, const int* in_sizes, int n_in,
                              void* d_out, int out_size, void* d_ws, size_t ws_size,
                              hipStream_t stream) {
  const float* X    = (const float*)d_in[0];
  const float* eW1  = (const float*)d_in[1];
  const float* eb1  = (const float*)d_in[2];
  const float* eg1  = (const float*)d_in[3];
  const float* ebe1 = (const float*)d_in[4];
  const float* eW2  = (const float*)d_in[5];
  const float* eb2  = (const float*)d_in[6];
  const float* CB   = (const float*)d_in[7];
  const float* dW1  = (const float*)d_in[8];
  const float* db1  = (const float*)d_in[9];
  const float* dg1  = (const float*)d_in[10];
  const float* dbe1 = (const float*)d_in[11];
  const float* dW2  = (const float*)d_in[12];
  const float* db2  = (const float*)d_in[13];
  float* out = (float*)d_out;

  char* wsb = (char*)d_ws;
  ushort_t* H1    = (ushort_t*)wsb;
  int* topics     = (int*)(wsb + 33554432);
  float* colsum   = (float*)(wsb + 34078720);
  float* colsumsq = colsum + 128;
  int* counts     = (int*)(wsb + 34078720 + 1024);
  float* Zloss    = (float*)(wsb + 34078720 + 3072);
  float* Rsum     = Zloss + 1;
  float* scale1   = (float*)(wsb + 34082816);
  float* shift1   = scale1 + 128;
  float* cn       = (float*)(wsb + 34083840);
  float* T        = (float*)(wsb + 34085888);
  float* scale2   = (float*)(wsb + 34348032);
  float* shift2   = scale2 + 128;
  float* U        = (float*)(wsb + 34349056);

  hipMemsetAsync(wsb + 34078720, 0, 4096, stream);

  k_gemm1<<<NROWS / 128, 256, 0, stream>>>(X, eW1, eb1, H1, colsum, colsumsq);
  k_bn1<<<1, 128, 0, stream>>>(colsum, colsumsq, eg1, ebe1, scale1, shift1);
  k_cn<<<1, 512, 0, stream>>>(CB, cn);
  k_encode<<<NROWS / 64, 256, 0, stream>>>(H1, scale1, shift1, eW2, eb2, CB, cn,
                                           topics, counts, Zloss);
  k_T<<<KCODES * HDIM / 256, 256, 0, stream>>>(CB, dW1, db1, T);
  k_bn2<<<1, 128, 0, stream>>>(counts, T, dg1, dbe1, scale2, shift2);
  k_U<<<KCODES * 2, 256, 0, stream>>>(T, scale2, shift2, dW2, db2, U);
  k_recon<<<1024, 256, 0, stream>>>(X, U, topics, Rsum);
  k_final<<<1, 1, 0, stream>>>(Zloss, Rsum, out);
}

// Round 3
// 302.487 us; speedup vs baseline: 1.5132x; 1.5132x over previous
//
#include <hip/hip_runtime.h>
#include <hip/hip_bf16.h>

// Problem constants (from setup_inputs)
#define NROWS 131072
#define DIN   512
#define HDIM  128
#define EDIM  32
#define KCODES 512

typedef unsigned short ushort_t;
typedef unsigned int   uint_t;
typedef float f32x4 __attribute__((ext_vector_type(4)));
typedef short s16x8 __attribute__((ext_vector_type(8)));

// ---------- bf16 helpers (manual, RNE pack) ----------
__device__ __forceinline__ float bflo(uint_t u) {
  union { uint_t u; float f; } x; x.u = u << 16; return x.f;
}
__device__ __forceinline__ float bfhi(uint_t u) {
  union { uint_t u; float f; } x; x.u = u & 0xffff0000u; return x.f;
}
__device__ __forceinline__ float bfu(ushort_t u) {
  union { uint_t u; float f; } x; x.u = ((uint_t)u) << 16; return x.f;
}
__device__ __forceinline__ ushort_t f2bf(float f) {
  union { float f; uint_t u; } x; x.f = f;
  uint_t u = x.u;
  return (ushort_t)((u + 0x7fffu + ((u >> 16) & 1u)) >> 16);
}

// ---------------------------------------------------------------------------
// W1t[n][k] = bf16(W1[k][n])  (128 x 512 bf16, 128 KB) — once per launch.
// ---------------------------------------------------------------------------
__global__ __launch_bounds__(256) void k_w1t(const float* __restrict__ W1,
                                             ushort_t* __restrict__ W1t)
{
  int gid = blockIdx.x * 256 + threadIdx.x;   // 65536
  int k = gid >> 7, n = gid & 127;
  W1t[n * 512 + k] = f2bf(W1[gid]);
}

// ---------------------------------------------------------------------------
// K1: H1 = X @ W1 + b1 via bf16 MFMA 16x16x32. BM=128, BN=128, BK=64.
// 4 waves (2x2), each 64x64 out = 4x4 fragments. A reg-staged fp32->bf16 into
// XOR-swizzled LDS; B frags loaded per-wave from L2-resident W1t.
// Epilogue: +bias, bf16 H1 write, BN col stats.
// ---------------------------------------------------------------------------
__global__ __launch_bounds__(256, 2) void k_gemm1(
    const float* __restrict__ X, const ushort_t* __restrict__ W1t,
    const float* __restrict__ b1, ushort_t* __restrict__ H1,
    float* __restrict__ colsum, float* __restrict__ colsumsq)
{
  __shared__ ushort_t Alds[128 * 64];   // swizzled: elem = r*64 + ((b^(r&7))<<3) + (k&7)
  __shared__ float lsum[128], lssq[128];
  const int tid = threadIdx.x;
  const int lane = tid & 63;
  const int wid = tid >> 6;
  const int wr = wid >> 1, wc = wid & 1;
  const size_t row0 = (size_t)blockIdx.x * 128;
  if (tid < 128) { lsum[tid] = 0.f; lssq[tid] = 0.f; }

  f32x4 acc[4][4];
#pragma unroll
  for (int i = 0; i < 4; ++i)
#pragma unroll
    for (int j = 0; j < 4; ++j) acc[i][j] = (f32x4)(0.f);

  // A staging pattern: thread covers k-quad k4 = tid&15 (fixed),
  // rows r = (tid>>4) + 16j, j=0..7  (128x64 fp32 tile = 2048 float4).
  const int k4 = tid & 15;
  const int rbase = tid >> 4;

  // B fragment global element offsets (per nf): col*512 + (lane>>4)*8
  int bofs[4];
#pragma unroll
  for (int nf = 0; nf < 4; ++nf) {
    int col = wc * 64 + nf * 16 + (lane & 15);
    bofs[nf] = col * 512 + (lane >> 4) * 8;
  }
  // A fragment LDS element offsets (per mf, km)
  int aofs[4][2];
#pragma unroll
  for (int mf = 0; mf < 4; ++mf) {
    int a_r = wr * 64 + mf * 16 + (lane & 15);
#pragma unroll
    for (int km = 0; km < 2; ++km) {
      int b = km * 4 + (lane >> 4);
      aofs[mf][km] = a_r * 64 + ((b ^ (a_r & 7)) << 3);
    }
  }

  // prologue: load tile 0
  float4 xa[8];
  s16x8 bfrag[4][2];
#pragma unroll
  for (int j = 0; j < 8; ++j)
    xa[j] = *(const float4*)(X + (row0 + rbase + 16 * j) * 512 + k4 * 4);
#pragma unroll
  for (int nf = 0; nf < 4; ++nf)
#pragma unroll
    for (int km = 0; km < 2; ++km)
      bfrag[nf][km] = *(const s16x8*)(W1t + bofs[nf] + km * 32);

#pragma unroll
  for (int it = 0; it < 8; ++it) {
    __syncthreads();   // all waves done reading Alds from prev iter
    // convert + swizzled LDS write of current A tile
#pragma unroll
    for (int j = 0; j < 8; ++j) {
      int r = rbase + 16 * j;
      uint2 p;
      p.x = (uint_t)f2bf(xa[j].x) | ((uint_t)f2bf(xa[j].y) << 16);
      p.y = (uint_t)f2bf(xa[j].z) | ((uint_t)f2bf(xa[j].w) << 16);
      *(uint2*)(Alds + r * 64 + (((k4 >> 1) ^ (r & 7)) << 3) + (k4 & 1) * 4) = p;
    }
    // prefetch next tile (HBM latency hides under barrier + compute)
    float4 xa2[8];
    s16x8 bf2[4][2];
    if (it < 7) {
      const int kc2 = (it + 1) * 64;
#pragma unroll
      for (int j = 0; j < 8; ++j)
        xa2[j] = *(const float4*)(X + (row0 + rbase + 16 * j) * 512 + kc2 + k4 * 4);
#pragma unroll
      for (int nf = 0; nf < 4; ++nf)
#pragma unroll
        for (int km = 0; km < 2; ++km)
          bf2[nf][km] = *(const s16x8*)(W1t + bofs[nf] + kc2 + km * 32);
    }
    __syncthreads();   // Alds ready
    s16x8 afrag[4][2];
#pragma unroll
    for (int mf = 0; mf < 4; ++mf)
#pragma unroll
      for (int km = 0; km < 2; ++km)
        afrag[mf][km] = *(const s16x8*)(Alds + aofs[mf][km]);
#pragma unroll
    for (int km = 0; km < 2; ++km)
#pragma unroll
      for (int mf = 0; mf < 4; ++mf)
#pragma unroll
        for (int nf = 0; nf < 4; ++nf)
          acc[mf][nf] = __builtin_amdgcn_mfma_f32_16x16x32_bf16(
              afrag[mf][km], bfrag[nf][km], acc[mf][nf], 0, 0, 0);
    if (it < 7) {
#pragma unroll
      for (int j = 0; j < 8; ++j) xa[j] = xa2[j];
#pragma unroll
      for (int nf = 0; nf < 4; ++nf)
#pragma unroll
        for (int km = 0; km < 2; ++km) bfrag[nf][km] = bf2[nf][km];
    }
  }

  // epilogue: +bias, bf16 H1, BN stats.
  // C/D layout: col = lane&15, row = (lane>>4)*4 + reg   [m89-verified]
  float bv[4]; int col[4];
#pragma unroll
  for (int nf = 0; nf < 4; ++nf) {
    col[nf] = wc * 64 + nf * 16 + (lane & 15);
    bv[nf] = b1[col[nf]];
  }
  float s[4] = {0.f, 0.f, 0.f, 0.f}, ss[4] = {0.f, 0.f, 0.f, 0.f};
#pragma unroll
  for (int mf = 0; mf < 4; ++mf) {
    size_t rowb = row0 + wr * 64 + mf * 16 + ((lane >> 4) << 2);
#pragma unroll
    for (int r = 0; r < 4; ++r) {
      size_t ro = (rowb + r) * 128;
#pragma unroll
      for (int nf = 0; nf < 4; ++nf) {
        float h = acc[mf][nf][r] + bv[nf];
        H1[ro + col[nf]] = f2bf(h);
        s[nf] += h; ss[nf] += h * h;
      }
    }
  }
#pragma unroll
  for (int nf = 0; nf < 4; ++nf) {
    atomicAdd(&lsum[col[nf]], s[nf]);
    atomicAdd(&lssq[col[nf]], ss[nf]);
  }
  __syncthreads();
  if (tid < 128) {
    atomicAdd(&colsum[tid], lsum[tid]);
    atomicAdd(&colsumsq[tid], lssq[tid]);
  }
}

// ---------------------------------------------------------------------------
// BN params for encoder: scale1 = g*rsqrt(var+eps), shift1 = be - mu*scale1
// ---------------------------------------------------------------------------
__global__ void k_bn1(const float* __restrict__ colsum,
                      const float* __restrict__ colsumsq,
                      const float* __restrict__ g, const float* __restrict__ be,
                      float* __restrict__ scale, float* __restrict__ shift)
{
  int j = threadIdx.x;
  float mu = colsum[j] * (1.f / NROWS);
  float var = colsumsq[j] * (1.f / NROWS) - mu * mu;
  float sc = g[j] * rsqrtf(var + 1e-5f);
  scale[j] = sc;
  shift[j] = be[j] - mu * sc;
}

// codebook row norms
__global__ void k_cn(const float* __restrict__ CB, float* __restrict__ cn)
{
  int k = threadIdx.x;  // 512
  float s = 0.f;
#pragma unroll
  for (int e = 0; e < EDIM; ++e) { float c = CB[k * EDIM + e]; s += c * c; }
  cn[k] = s;
}

// ---------------------------------------------------------------------------
// K3: fused BN+ReLU -> Z = Hb@W2+b2 -> nearest-code argmin.
// 64 rows/block, grid 2048 x 256.
// ---------------------------------------------------------------------------
__global__ __launch_bounds__(256, 2) void k_encode(
    const ushort_t* __restrict__ H1, const float* __restrict__ scale1,
    const float* __restrict__ shift1, const float* __restrict__ W2,
    const float* __restrict__ b2, const float* __restrict__ CB,
    const float* __restrict__ cn, int* __restrict__ topics,
    int* __restrict__ counts, float* __restrict__ Zloss)
{
  __shared__ ushort_t Hb[64 * 136];    // bf16 activations
  __shared__ ushort_t cbl[512 * 36];   // bf16 codebook
  __shared__ float Zt[64 * 33];        // fp32 Z tile
  __shared__ int hist[512];
  __shared__ float zsh;

  const int tid = threadIdx.x;
  const int row0 = blockIdx.x * 64;

  hist[tid] = 0; hist[tid + 256] = 0;
  if (tid == 0) zsh = 0.f;

  // ---- phase 0a: stage H1 tile with BN+ReLU applied ----
  {
    const int r0 = tid >> 4;          // 0..15
    const int c0 = (tid * 8) & 127;   // multiple of 8
    float sc[8], sh[8];
    {
      float4 a = *(const float4*)(scale1 + c0);
      float4 b = *(const float4*)(scale1 + c0 + 4);
      sc[0]=a.x; sc[1]=a.y; sc[2]=a.z; sc[3]=a.w; sc[4]=b.x; sc[5]=b.y; sc[6]=b.z; sc[7]=b.w;
      float4 e = *(const float4*)(shift1 + c0);
      float4 f = *(const float4*)(shift1 + c0 + 4);
      sh[0]=e.x; sh[1]=e.y; sh[2]=e.z; sh[3]=e.w; sh[4]=f.x; sh[5]=f.y; sh[6]=f.z; sh[7]=f.w;
    }
#pragma unroll
    for (int it = 0; it < 4; ++it) {
      int r = r0 + it * 16;
      uint4 v = *(const uint4*)(H1 + (size_t)(row0 + r) * HDIM + c0);
      uint_t u[4] = {v.x, v.y, v.z, v.w};
      uint_t o[4];
#pragma unroll
      for (int m = 0; m < 4; ++m) {
        float f0 = fmaxf(bflo(u[m]) * sc[2*m]   + sh[2*m],   0.f);
        float f1 = fmaxf(bfhi(u[m]) * sc[2*m+1] + sh[2*m+1], 0.f);
        o[m] = (uint_t)f2bf(f0) | ((uint_t)f2bf(f1) << 16);
      }
      *(uint4*)(Hb + r * 136 + c0) = make_uint4(o[0], o[1], o[2], o[3]);
    }
  }
  // ---- phase 0b: stage codebook as bf16 ----
  {
#pragma unroll
    for (int it = 0; it < 16; ++it) {
      int f = tid + it * 256;   // float4 index
      int c = f >> 3;
      int e4 = (f & 7) * 4;
      float4 v = *(const float4*)(CB + (size_t)c * EDIM + e4);
      ushort_t* p = cbl + c * 36 + e4;
      p[0] = f2bf(v.x); p[1] = f2bf(v.y); p[2] = f2bf(v.z); p[3] = f2bf(v.w);
    }
  }
  __syncthreads();

  // ---- phase 1: Z = Hb @ W2 + b2 (2 rows x 4 cols per thread) ----
  {
    const int rowg = tid >> 3;
    const int colg = tid & 7;
    const int hb0 = (rowg * 2) * 136;
    const int hb1 = hb0 + 136;
    float za00=0,za01=0,za02=0,za03=0, za10=0,za11=0,za12=0,za13=0;
#pragma unroll 4
    for (int k = 0; k < HDIM; ++k) {
      float h0 = bfu(Hb[hb0 + k]);
      float h1 = bfu(Hb[hb1 + k]);
      float4 w = *(const float4*)(W2 + k * EDIM + colg * 4);
      za00 += h0 * w.x; za01 += h0 * w.y; za02 += h0 * w.z; za03 += h0 * w.w;
      za10 += h1 * w.x; za11 += h1 * w.y; za12 += h1 * w.z; za13 += h1 * w.w;
    }
    float4 bb = *(const float4*)(b2 + colg * 4);
    int zb = (rowg * 2) * 33 + colg * 4;
    Zt[zb + 0] = za00 + bb.x; Zt[zb + 1] = za01 + bb.y;
    Zt[zb + 2] = za02 + bb.z; Zt[zb + 3] = za03 + bb.w;
    Zt[zb + 33 + 0] = za10 + bb.x; Zt[zb + 33 + 1] = za11 + bb.y;
    Zt[zb + 33 + 2] = za12 + bb.z; Zt[zb + 33 + 3] = za13 + bb.w;
  }
  __syncthreads();

  // ---- phase 2: distances + argmin ----
  {
    const int rp = tid >> 3;
    const int q = tid & 7;
    float z0[32], z1[32];
    float zn0 = 0.f, zn1 = 0.f;
#pragma unroll
    for (int e = 0; e < 32; ++e) {
      z0[e] = Zt[rp * 33 + e];        zn0 += z0[e] * z0[e];
      z1[e] = Zt[(rp + 32) * 33 + e]; zn1 += z1[e] * z1[e];
    }
    float minv0 = 3.4e38f, minv1 = 3.4e38f;
    int mini0 = 0, mini1 = 0;
    for (int i = 0; i < 64; ++i) {
      const int c = i * 8 + q;
      const ushort_t* cp = cbl + c * 36;
      float d0a = 0.f, d0b = 0.f, d1a = 0.f, d1b = 0.f;
#pragma unroll
      for (int e4 = 0; e4 < 8; e4 += 2) {
        uint2 wa = *(const uint2*)(cp + e4 * 4);
        uint2 wb = *(const uint2*)(cp + e4 * 4 + 4);
        float w0 = bflo(wa.x), w1 = bfhi(wa.x), w2 = bflo(wa.y), w3 = bfhi(wa.y);
        float w4 = bflo(wb.x), w5 = bfhi(wb.x), w6 = bflo(wb.y), w7 = bfhi(wb.y);
        const int e = e4 * 4;
        d0a += z0[e+0]*w0 + z0[e+1]*w1 + z0[e+2]*w2 + z0[e+3]*w3;
        d0b += z0[e+4]*w4 + z0[e+5]*w5 + z0[e+6]*w6 + z0[e+7]*w7;
        d1a += z1[e+0]*w0 + z1[e+1]*w1 + z1[e+2]*w2 + z1[e+3]*w3;
        d1b += z1[e+4]*w4 + z1[e+5]*w5 + z1[e+6]*w6 + z1[e+7]*w7;
      }
      float cc = cn[c];
      float d0 = cc - 2.f * (d0a + d0b);
      float d1 = cc - 2.f * (d1a + d1b);
      if (d0 < minv0) { minv0 = d0; mini0 = c; }
      if (d1 < minv1) { minv1 = d1; mini1 = c; }
    }
#pragma unroll
    for (int m = 1; m < 8; m <<= 1) {
      float ov = __shfl_xor(minv0, m, 64); int oi = __shfl_xor(mini0, m, 64);
      if (ov < minv0 || (ov == minv0 && oi < mini0)) { minv0 = ov; mini0 = oi; }
      ov = __shfl_xor(minv1, m, 64); oi = __shfl_xor(mini1, m, 64);
      if (ov < minv1 || (ov == minv1 && oi < mini1)) { minv1 = ov; mini1 = oi; }
    }
    if (q == 0) {
      topics[row0 + rp] = mini0;
      topics[row0 + rp + 32] = mini1;
      atomicAdd(&hist[mini0], 1);
      atomicAdd(&hist[mini1], 1);
      atomicAdd(&zsh, (minv0 + zn0) + (minv1 + zn1));
    }
  }
  __syncthreads();
  {
    int h0 = hist[tid], h1 = hist[tid + 256];
    if (h0) atomicAdd(&counts[tid], h0);
    if (h1) atomicAdd(&counts[tid + 256], h1);
    if (tid == 0) atomicAdd(Zloss, zsh);
  }
}

// ---------------------------------------------------------------------------
// Decoder table T = codebook @ dec_W1 + dec_b1   [512 x 128]
// ---------------------------------------------------------------------------
__global__ __launch_bounds__(256) void k_T(const float* __restrict__ CB,
    const float* __restrict__ dW1, const float* __restrict__ db1,
    float* __restrict__ T)
{
  int gid = blockIdx.x * 256 + threadIdx.x;
  int k = gid >> 7, j = gid & 127;
  float acc = db1[j];
#pragma unroll
  for (int e = 0; e < EDIM; ++e) acc += CB[k * EDIM + e] * dW1[e * HDIM + j];
  T[gid] = acc;
}

// Decoder BN params from topic histogram (exact batch stats)
__global__ void k_bn2(const int* __restrict__ counts, const float* __restrict__ T,
    const float* __restrict__ g, const float* __restrict__ be,
    float* __restrict__ scale2, float* __restrict__ shift2)
{
  __shared__ float cw[512];
  int j = threadIdx.x;  // 128
  for (int i = j; i < 512; i += 128) cw[i] = (float)counts[i];
  __syncthreads();
  float s = 0.f, ss = 0.f;
  for (int k = 0; k < KCODES; ++k) {
    float t = T[k * HDIM + j];
    float c = cw[k];
    s += c * t; ss += c * t * t;
  }
  float mu = s * (1.f / NROWS);
  float var = ss * (1.f / NROWS) - mu * mu;
  float sc = g[j] * rsqrtf(var + 1e-5f);
  scale2[j] = sc;
  shift2[j] = be[j] - mu * sc;
}

// U = relu(bn(T)) @ dec_W2 + dec_b2   [512 x 512]
__global__ __launch_bounds__(256) void k_U(const float* __restrict__ T,
    const float* __restrict__ scale2, const float* __restrict__ shift2,
    const float* __restrict__ dW2, const float* __restrict__ db2,
    float* __restrict__ U)
{
  __shared__ float Tb[128];
  const int tid = threadIdx.x;
  const int k = blockIdx.x >> 1;
  const int c = (blockIdx.x & 1) * 256 + tid;
  if (tid < 128) Tb[tid] = fmaxf(T[k * HDIM + tid] * scale2[tid] + shift2[tid], 0.f);
  __syncthreads();
  float acc = db2[c];
#pragma unroll 8
  for (int j = 0; j < HDIM; ++j) acc += Tb[j] * dW2[j * 512 + c];
  U[(size_t)k * 512 + c] = acc;
}

// Reconstruction: R += sum_n ||U[topic[n]] - X[n]||^2
__global__ __launch_bounds__(256, 4) void k_recon(
    const float* __restrict__ X, const float* __restrict__ U,
    const int* __restrict__ topics, float* __restrict__ Rsum)
{
  __shared__ float bsum;
  const int tid = threadIdx.x;
  if (tid == 0) bsum = 0.f;
  __syncthreads();
  const int lane = tid & 63;
  const int wave = blockIdx.x * 4 + (tid >> 6);
  float acc = 0.f;
  for (int r = wave; r < NROWS; r += 4096) {
    const int t = topics[r];
    const float4* xr = (const float4*)(X + (size_t)r * DIN);
    const float4* ur = (const float4*)(U + (size_t)t * 512);
    float4 x0 = xr[lane],      u0 = ur[lane];
    float4 x1 = xr[lane + 64], u1 = ur[lane + 64];
    float d;
    d = x0.x - u0.x; acc += d * d;
    d = x0.y - u0.y; acc += d * d;
    d = x0.z - u0.z; acc += d * d;
    d = x0.w - u0.w; acc += d * d;
    d = x1.x - u1.x; acc += d * d;
    d = x1.y - u1.y; acc += d * d;
    d = x1.z - u1.z; acc += d * d;
    d = x1.w - u1.w; acc += d * d;
  }
#pragma unroll
  for (int off = 32; off > 0; off >>= 1) acc += __shfl_down(acc, off, 64);
  if (lane == 0) atomicAdd(&bsum, acc);
  __syncthreads();
  if (tid == 0) atomicAdd(Rsum, bsum);
}

__global__ void k_final(const float* __restrict__ Zloss,
                        const float* __restrict__ Rsum, float* __restrict__ out)
{
  // C_loss == Z_loss in forward (stop_gradient is identity forward)
  out[0] = 2.f * Zloss[0] + sqrtf(Rsum[0]);
}

// ---------------------------------------------------------------------------
// Workspace layout (bytes):                              total ~35.4 MB
//   0         H1 bf16            [N*128]      33,554,432
//   33554432  topics int32       [N]             524,288
//   34078720  accumulators (memset 0 each launch, 4 KB)
//   34082816  scale1[128]+shift1[128]
//   34083840  cn[512]
//   34085888  T[512*128]                       262,144
//   34348032  scale2[128]+shift2[128]
//   34349056  U[512*512]                     1,048,576
//     NOTE: W1t (128 KB bf16) aliases the U region — lifetimes disjoint
//           (W1t: [k_w1t .. k_gemm1], U: [k_U .. k_recon]).
// ---------------------------------------------------------------------------
extern "C" void kernel_launch(void* const* d_in, const int* in_sizes, int n_in,
                              void* d_out, int out_size, void* d_ws, size_t ws_size,
                              hipStream_t stream) {
  const float* X    = (const float*)d_in[0];
  const float* eW1  = (const float*)d_in[1];
  const float* eb1  = (const float*)d_in[2];
  const float* eg1  = (const float*)d_in[3];
  const float* ebe1 = (const float*)d_in[4];
  const float* eW2  = (const float*)d_in[5];
  const float* eb2  = (const float*)d_in[6];
  const float* CB   = (const float*)d_in[7];
  const float* dW1  = (const float*)d_in[8];
  const float* db1  = (const float*)d_in[9];
  const float* dg1  = (const float*)d_in[10];
  const float* dbe1 = (const float*)d_in[11];
  const float* dW2  = (const float*)d_in[12];
  const float* db2  = (const float*)d_in[13];
  float* out = (float*)d_out;

  char* wsb = (char*)d_ws;
  ushort_t* H1    = (ushort_t*)wsb;
  int* topics     = (int*)(wsb + 33554432);
  float* colsum   = (float*)(wsb + 34078720);
  float* colsumsq = colsum + 128;
  int* counts     = (int*)(wsb + 34078720 + 1024);
  float* Zloss    = (float*)(wsb + 34078720 + 3072);
  float* Rsum     = Zloss + 1;
  float* scale1   = (float*)(wsb + 34082816);
  float* shift1   = scale1 + 128;
  float* cn       = (float*)(wsb + 34083840);
  float* T        = (float*)(wsb + 34085888);
  float* scale2   = (float*)(wsb + 34348032);
  float* shift2   = scale2 + 128;
  float* U        = (float*)(wsb + 34349056);
  ushort_t* W1t   = (ushort_t*)(wsb + 34349056);  // aliases U (disjoint lifetime)

  hipMemsetAsync(wsb + 34078720, 0, 4096, stream);

  k_w1t<<<256, 256, 0, stream>>>(eW1, W1t);
  k_gemm1<<<NROWS / 128, 256, 0, stream>>>(X, W1t, eb1, H1, colsum, colsumsq);
  k_bn1<<<1, 128, 0, stream>>>(colsum, colsumsq, eg1, ebe1, scale1, shift1);
  k_cn<<<1, 512, 0, stream>>>(CB, cn);
  k_encode<<<NROWS / 64, 256, 0, stream>>>(H1, scale1, shift1, eW2, eb2, CB, cn,
                                           topics, counts, Zloss);
  k_T<<<KCODES * HDIM / 256, 256, 0, stream>>>(CB, dW1, db1, T);
  k_bn2<<<1, 128, 0, stream>>>(counts, T, dg1, dbe1, scale2, shift2);
  k_U<<<KCODES * 2, 256, 0, stream>>>(T, scale2, shift2, dW2, db2, U);
  k_recon<<<1024, 256, 0, stream>>>(X, U, topics, Rsum);
  k_final<<<1, 1, 0, stream>>>(Zloss, Rsum, out);
}

// Round 4
// 223.370 us; speedup vs baseline: 2.0491x; 1.3542x over previous
//
#include <hip/hip_runtime.h>
#include <hip/hip_bf16.h>

// Problem constants (from setup_inputs)
#define NROWS 131072
#define DIN   512
#define HDIM  128
#define EDIM  32
#define KCODES 512

typedef unsigned short ushort_t;
typedef unsigned int   uint_t;
typedef float f32x4 __attribute__((ext_vector_type(4)));
typedef short s16x8 __attribute__((ext_vector_type(8)));

// ---------- bf16 helpers (manual, RNE pack) ----------
__device__ __forceinline__ float bflo(uint_t u) {
  union { uint_t u; float f; } x; x.u = u << 16; return x.f;
}
__device__ __forceinline__ float bfhi(uint_t u) {
  union { uint_t u; float f; } x; x.u = u & 0xffff0000u; return x.f;
}
__device__ __forceinline__ ushort_t f2bf(float f) {
  union { float f; uint_t u; } x; x.f = f;
  uint_t u = x.u;
  return (ushort_t)((u + 0x7fffu + ((u >> 16) & 1u)) >> 16);
}

// ---------------------------------------------------------------------------
// k_prep: build W1t (bf16 [n][k] 128x512), W2t (bf16 [e][k] 32x128),
// CBb (bf16 [c][e] 512x32), cn (fp32 codebook row norms), zero accumulators.
// grid 256 x 256.
// ---------------------------------------------------------------------------
__global__ __launch_bounds__(256) void k_prep(
    const float* __restrict__ W1, const float* __restrict__ W2,
    const float* __restrict__ CB,
    ushort_t* __restrict__ W1t, ushort_t* __restrict__ W2t,
    ushort_t* __restrict__ CBb, float* __restrict__ cn,
    float* __restrict__ accz)
{
  int gid = blockIdx.x * 256 + threadIdx.x;   // 0..65535
  {
    int k = gid >> 7, n = gid & 127;
    W1t[n * 512 + k] = f2bf(W1[gid]);         // W1 is [k][n] = [512][128]
  }
  if (gid < 16384) CBb[gid] = f2bf(CB[gid]);  // CB already [c][e]
  if (gid < 4096) {
    int e = gid >> 7, k = gid & 127;
    W2t[gid] = f2bf(W2[k * 32 + e]);          // W2 is [k][e] = [128][32]
  }
  if (gid < 512) {
    float s = 0.f;
#pragma unroll
    for (int e = 0; e < EDIM; ++e) { float c = CB[gid * EDIM + e]; s += c * c; }
    cn[gid] = s;
  }
  if (gid < 1024) accz[gid] = 0.f;            // colsum/colsumsq/counts/Zloss/Rsum
}

// ---------------------------------------------------------------------------
// K1: H1 = X @ W1 + b1 via bf16 MFMA 16x16x32. BM=128, BN=128, BK=64.
// (unchanged from round 2 — validated)
// ---------------------------------------------------------------------------
__global__ __launch_bounds__(256, 2) void k_gemm1(
    const float* __restrict__ X, const ushort_t* __restrict__ W1t,
    const float* __restrict__ b1, ushort_t* __restrict__ H1,
    float* __restrict__ colsum, float* __restrict__ colsumsq)
{
  __shared__ ushort_t Alds[128 * 64];   // swizzled
  __shared__ float lsum[128], lssq[128];
  const int tid = threadIdx.x;
  const int lane = tid & 63;
  const int wid = tid >> 6;
  const int wr = wid >> 1, wc = wid & 1;
  const size_t row0 = (size_t)blockIdx.x * 128;
  if (tid < 128) { lsum[tid] = 0.f; lssq[tid] = 0.f; }

  f32x4 acc[4][4];
#pragma unroll
  for (int i = 0; i < 4; ++i)
#pragma unroll
    for (int j = 0; j < 4; ++j) acc[i][j] = (f32x4)(0.f);

  const int k4 = tid & 15;
  const int rbase = tid >> 4;

  int bofs[4];
#pragma unroll
  for (int nf = 0; nf < 4; ++nf) {
    int col = wc * 64 + nf * 16 + (lane & 15);
    bofs[nf] = col * 512 + (lane >> 4) * 8;
  }
  int aofs[4][2];
#pragma unroll
  for (int mf = 0; mf < 4; ++mf) {
    int a_r = wr * 64 + mf * 16 + (lane & 15);
#pragma unroll
    for (int km = 0; km < 2; ++km) {
      int b = km * 4 + (lane >> 4);
      aofs[mf][km] = a_r * 64 + ((b ^ (a_r & 7)) << 3);
    }
  }

  float4 xa[8];
  s16x8 bfrag[4][2];
#pragma unroll
  for (int j = 0; j < 8; ++j)
    xa[j] = *(const float4*)(X + (row0 + rbase + 16 * j) * 512 + k4 * 4);
#pragma unroll
  for (int nf = 0; nf < 4; ++nf)
#pragma unroll
    for (int km = 0; km < 2; ++km)
      bfrag[nf][km] = *(const s16x8*)(W1t + bofs[nf] + km * 32);

#pragma unroll
  for (int it = 0; it < 8; ++it) {
    __syncthreads();
#pragma unroll
    for (int j = 0; j < 8; ++j) {
      int r = rbase + 16 * j;
      uint2 p;
      p.x = (uint_t)f2bf(xa[j].x) | ((uint_t)f2bf(xa[j].y) << 16);
      p.y = (uint_t)f2bf(xa[j].z) | ((uint_t)f2bf(xa[j].w) << 16);
      *(uint2*)(Alds + r * 64 + (((k4 >> 1) ^ (r & 7)) << 3) + (k4 & 1) * 4) = p;
    }
    float4 xa2[8];
    s16x8 bf2[4][2];
    if (it < 7) {
      const int kc2 = (it + 1) * 64;
#pragma unroll
      for (int j = 0; j < 8; ++j)
        xa2[j] = *(const float4*)(X + (row0 + rbase + 16 * j) * 512 + kc2 + k4 * 4);
#pragma unroll
      for (int nf = 0; nf < 4; ++nf)
#pragma unroll
        for (int km = 0; km < 2; ++km)
          bf2[nf][km] = *(const s16x8*)(W1t + bofs[nf] + kc2 + km * 32);
    }
    __syncthreads();
    s16x8 afrag[4][2];
#pragma unroll
    for (int mf = 0; mf < 4; ++mf)
#pragma unroll
      for (int km = 0; km < 2; ++km)
        afrag[mf][km] = *(const s16x8*)(Alds + aofs[mf][km]);
#pragma unroll
    for (int km = 0; km < 2; ++km)
#pragma unroll
      for (int mf = 0; mf < 4; ++mf)
#pragma unroll
        for (int nf = 0; nf < 4; ++nf)
          acc[mf][nf] = __builtin_amdgcn_mfma_f32_16x16x32_bf16(
              afrag[mf][km], bfrag[nf][km], acc[mf][nf], 0, 0, 0);
    if (it < 7) {
#pragma unroll
      for (int j = 0; j < 8; ++j) xa[j] = xa2[j];
#pragma unroll
      for (int nf = 0; nf < 4; ++nf)
#pragma unroll
        for (int km = 0; km < 2; ++km) bfrag[nf][km] = bf2[nf][km];
    }
  }

  float bv[4]; int col[4];
#pragma unroll
  for (int nf = 0; nf < 4; ++nf) {
    col[nf] = wc * 64 + nf * 16 + (lane & 15);
    bv[nf] = b1[col[nf]];
  }
  float s[4] = {0.f, 0.f, 0.f, 0.f}, ss[4] = {0.f, 0.f, 0.f, 0.f};
#pragma unroll
  for (int mf = 0; mf < 4; ++mf) {
    size_t rowb = row0 + wr * 64 + mf * 16 + ((lane >> 4) << 2);
#pragma unroll
    for (int r = 0; r < 4; ++r) {
      size_t ro = (rowb + r) * 128;
#pragma unroll
      for (int nf = 0; nf < 4; ++nf) {
        float h = acc[mf][nf][r] + bv[nf];
        H1[ro + col[nf]] = f2bf(h);
        s[nf] += h; ss[nf] += h * h;
      }
    }
  }
#pragma unroll
  for (int nf = 0; nf < 4; ++nf) {
    atomicAdd(&lsum[col[nf]], s[nf]);
    atomicAdd(&lssq[col[nf]], ss[nf]);
  }
  __syncthreads();
  if (tid < 128) {
    atomicAdd(&colsum[tid], lsum[tid]);
    atomicAdd(&colsumsq[tid], lssq[tid]);
  }
}

// ---------------------------------------------------------------------------
// BN params for encoder
// ---------------------------------------------------------------------------
__global__ void k_bn1(const float* __restrict__ colsum,
                      const float* __restrict__ colsumsq,
                      const float* __restrict__ g, const float* __restrict__ be,
                      float* __restrict__ scale, float* __restrict__ shift)
{
  int j = threadIdx.x;
  float mu = colsum[j] * (1.f / NROWS);
  float var = colsumsq[j] * (1.f / NROWS) - mu * mu;
  float sc = g[j] * rsqrtf(var + 1e-5f);
  scale[j] = sc;
  shift[j] = be[j] - mu * sc;
}

// ---------------------------------------------------------------------------
// K3 (MFMA rewrite): BN+ReLU -> Z = Hb@W2+b2 (MFMA) -> dists Z@CBb^T (MFMA,
// K=32 in one instruction) + argmin. 64 rows/block, 4 waves x 16 rows.
// ---------------------------------------------------------------------------
__global__ __launch_bounds__(256, 4) void k_encode(
    const ushort_t* __restrict__ H1, const float* __restrict__ scale1,
    const float* __restrict__ shift1, const ushort_t* __restrict__ W2t,
    const float* __restrict__ b2, const ushort_t* __restrict__ CBb,
    const float* __restrict__ cn, int* __restrict__ topics,
    int* __restrict__ counts, float* __restrict__ Zloss)
{
  __shared__ ushort_t Hb[64 * 128];   // bf16, XOR-swizzled 8-elem blocks
  __shared__ float Zt[64 * 33];       // fp32 Z tile, stride 33 (transpose hop)
  __shared__ int hist[512];
  __shared__ float zsh;

  const int tid = threadIdx.x;
  const int lane = tid & 63;
  const int w = tid >> 6;
  const int lr = lane & 15;      // fragment row/col-within-16
  const int lk = lane >> 4;      // fragment k-block
  const int row0 = blockIdx.x * 64;

  hist[tid] = 0; hist[tid + 256] = 0;
  if (tid == 0) zsh = 0.f;

  // ---- stage Hb: BN+ReLU applied, bf16, swizzled ----
  {
    const int c8 = (tid & 15) * 8;      // col block (8 cols)
    const int rb = tid >> 4;            // row 0..15 (+16j)
    float sc[8], sh[8];
    {
      float4 a = *(const float4*)(scale1 + c8);
      float4 b = *(const float4*)(scale1 + c8 + 4);
      sc[0]=a.x; sc[1]=a.y; sc[2]=a.z; sc[3]=a.w; sc[4]=b.x; sc[5]=b.y; sc[6]=b.z; sc[7]=b.w;
      float4 e = *(const float4*)(shift1 + c8);
      float4 f = *(const float4*)(shift1 + c8 + 4);
      sh[0]=e.x; sh[1]=e.y; sh[2]=e.z; sh[3]=e.w; sh[4]=f.x; sh[5]=f.y; sh[6]=f.z; sh[7]=f.w;
    }
#pragma unroll
    for (int j = 0; j < 4; ++j) {
      int r = rb + 16 * j;
      uint4 v = *(const uint4*)(H1 + (size_t)(row0 + r) * HDIM + c8);
      uint_t u[4] = {v.x, v.y, v.z, v.w};
      uint4 o;
      uint_t* op = (uint_t*)&o;
#pragma unroll
      for (int m = 0; m < 4; ++m) {
        float f0 = fmaxf(bflo(u[m]) * sc[2*m]   + sh[2*m],   0.f);
        float f1 = fmaxf(bfhi(u[m]) * sc[2*m+1] + sh[2*m+1], 0.f);
        op[m] = (uint_t)f2bf(f0) | ((uint_t)f2bf(f1) << 16);
      }
      *(uint4*)(Hb + r * 128 + ((((c8 >> 3) ^ (r & 7))) << 3)) = o;
    }
  }
  __syncthreads();

  // ---- phase A: Z[w*16..+15][0..31] = Hb @ W2t + b2 (MFMA, K=128) ----
  float zn4[4];
  {
    s16x8 af[4];
#pragma unroll
    for (int kt = 0; kt < 4; ++kt) {
      int m = w * 16 + lr;
      int b = kt * 4 + lk;
      af[kt] = *(const s16x8*)(Hb + m * 128 + ((b ^ (m & 7)) << 3));
    }
    f32x4 zacc[2];
    zacc[0] = (f32x4)(0.f); zacc[1] = (f32x4)(0.f);
#pragma unroll
    for (int ct = 0; ct < 2; ++ct)
#pragma unroll
      for (int kt = 0; kt < 4; ++kt) {
        s16x8 bf = *(const s16x8*)(W2t + (ct * 16 + lr) * 128 + kt * 32 + lk * 8);
        zacc[ct] = __builtin_amdgcn_mfma_f32_16x16x32_bf16(af[kt], bf, zacc[ct], 0, 0, 0);
      }
    float bias0 = b2[lr], bias1 = b2[16 + lr];
    float s4[4];
#pragma unroll
    for (int r = 0; r < 4; ++r) {
      float z0 = zacc[0][r] + bias0;
      float z1 = zacc[1][r] + bias1;
      int row = w * 16 + lk * 4 + r;
      Zt[row * 33 + lr] = z0;
      Zt[row * 33 + 16 + lr] = z1;
      s4[r] = z0 * z0 + z1 * z1;
    }
    // row-norm reduce across the 16 cols (lanes sharing lk)
#pragma unroll
    for (int m = 1; m < 16; m <<= 1) {
#pragma unroll
      for (int r = 0; r < 4; ++r) s4[r] += __shfl_xor(s4[r], m, 64);
    }
#pragma unroll
    for (int r = 0; r < 4; ++r) zn4[r] = s4[r];
  }
  __syncthreads();

  // ---- phase B: distances via MFMA (K=32), running argmin ----
  {
    // A-frag: Z row m = w*16+lr, e = lk*8..+7 (bf16)
    s16x8 za;
    {
      const float* zp = Zt + (w * 16 + lr) * 33 + lk * 8;
      float4 q0 = *(const float4*)(zp);
      float4 q1 = *(const float4*)(zp + 4);
      za[0] = (short)f2bf(q0.x); za[1] = (short)f2bf(q0.y);
      za[2] = (short)f2bf(q0.z); za[3] = (short)f2bf(q0.w);
      za[4] = (short)f2bf(q1.x); za[5] = (short)f2bf(q1.y);
      za[6] = (short)f2bf(q1.z); za[7] = (short)f2bf(q1.w);
    }
    float minv[4] = {3.4e38f, 3.4e38f, 3.4e38f, 3.4e38f};
    int mini[4] = {0, 0, 0, 0};
#pragma unroll 4
    for (int t = 0; t < 32; ++t) {
      const int c = t * 16 + lr;
      s16x8 cb = *(const s16x8*)(CBb + c * 32 + lk * 8);
      f32x4 dot = __builtin_amdgcn_mfma_f32_16x16x32_bf16(za, cb, (f32x4)(0.f), 0, 0, 0);
      float cnv = cn[c];
#pragma unroll
      for (int r = 0; r < 4; ++r) {
        float d = fmaf(-2.f, dot[r], cnv);
        if (d < minv[r]) { minv[r] = d; mini[r] = c; }
      }
    }
    // reduce across the 16 code-columns (lanes sharing lk), first-min tie-break
#pragma unroll
    for (int m = 1; m < 16; m <<= 1) {
#pragma unroll
      for (int r = 0; r < 4; ++r) {
        float ov = __shfl_xor(minv[r], m, 64);
        int   oi = __shfl_xor(mini[r], m, 64);
        if (ov < minv[r] || (ov == minv[r] && oi < mini[r])) { minv[r] = ov; mini[r] = oi; }
      }
    }
    if (lr == 0) {
      float part = 0.f;
#pragma unroll
      for (int r = 0; r < 4; ++r) {
        int row = row0 + w * 16 + lk * 4 + r;
        topics[row] = mini[r];
        atomicAdd(&hist[mini[r]], 1);
        part += minv[r] + zn4[r];
      }
      atomicAdd(&zsh, part);
    }
  }
  __syncthreads();
  {
    int h0 = hist[tid], h1 = hist[tid + 256];
    if (h0) atomicAdd(&counts[tid], h0);
    if (h1) atomicAdd(&counts[tid + 256], h1);
    if (tid == 0) atomicAdd(Zloss, zsh);
  }
}

// ---------------------------------------------------------------------------
// Decoder table T = codebook @ dec_W1 + dec_b1   [512 x 128]
// ---------------------------------------------------------------------------
__global__ __launch_bounds__(256) void k_T(const float* __restrict__ CB,
    const float* __restrict__ dW1, const float* __restrict__ db1,
    float* __restrict__ T)
{
  int gid = blockIdx.x * 256 + threadIdx.x;
  int k = gid >> 7, j = gid & 127;
  float acc = db1[j];
#pragma unroll
  for (int e = 0; e < EDIM; ++e) acc += CB[k * EDIM + e] * dW1[e * HDIM + j];
  T[gid] = acc;
}

// Decoder BN params from topic histogram (exact batch stats)
__global__ void k_bn2(const int* __restrict__ counts, const float* __restrict__ T,
    const float* __restrict__ g, const float* __restrict__ be,
    float* __restrict__ scale2, float* __restrict__ shift2)
{
  __shared__ float cw[512];
  int j = threadIdx.x;  // 128
  for (int i = j; i < 512; i += 128) cw[i] = (float)counts[i];
  __syncthreads();
  float s = 0.f, ss = 0.f;
  for (int k = 0; k < KCODES; ++k) {
    float t = T[k * HDIM + j];
    float c = cw[k];
    s += c * t; ss += c * t * t;
  }
  float mu = s * (1.f / NROWS);
  float var = ss * (1.f / NROWS) - mu * mu;
  float sc = g[j] * rsqrtf(var + 1e-5f);
  scale2[j] = sc;
  shift2[j] = be[j] - mu * sc;
}

// U = relu(bn(T)) @ dec_W2 + dec_b2   [512 x 512]
__global__ __launch_bounds__(256) void k_U(const float* __restrict__ T,
    const float* __restrict__ scale2, const float* __restrict__ shift2,
    const float* __restrict__ dW2, const float* __restrict__ db2,
    float* __restrict__ U)
{
  __shared__ float Tb[128];
  const int tid = threadIdx.x;
  const int k = blockIdx.x >> 1;
  const int c = (blockIdx.x & 1) * 256 + tid;
  if (tid < 128) Tb[tid] = fmaxf(T[k * HDIM + tid] * scale2[tid] + shift2[tid], 0.f);
  __syncthreads();
  float acc = db2[c];
#pragma unroll 8
  for (int j = 0; j < HDIM; ++j) acc += Tb[j] * dW2[j * 512 + c];
  U[(size_t)k * 512 + c] = acc;
}

// Reconstruction: R += sum_n ||U[topic[n]] - X[n]||^2
__global__ __launch_bounds__(256, 4) void k_recon(
    const float* __restrict__ X, const float* __restrict__ U,
    const int* __restrict__ topics, float* __restrict__ Rsum)
{
  __shared__ float bsum;
  const int tid = threadIdx.x;
  if (tid == 0) bsum = 0.f;
  __syncthreads();
  const int lane = tid & 63;
  const int wave = blockIdx.x * 4 + (tid >> 6);
  float acc = 0.f;
  for (int r = wave; r < NROWS; r += 4096) {
    const int t = topics[r];
    const float4* xr = (const float4*)(X + (size_t)r * DIN);
    const float4* ur = (const float4*)(U + (size_t)t * 512);
    float4 x0 = xr[lane],      u0 = ur[lane];
    float4 x1 = xr[lane + 64], u1 = ur[lane + 64];
    float d;
    d = x0.x - u0.x; acc += d * d;
    d = x0.y - u0.y; acc += d * d;
    d = x0.z - u0.z; acc += d * d;
    d = x0.w - u0.w; acc += d * d;
    d = x1.x - u1.x; acc += d * d;
    d = x1.y - u1.y; acc += d * d;
    d = x1.z - u1.z; acc += d * d;
    d = x1.w - u1.w; acc += d * d;
  }
#pragma unroll
  for (int off = 32; off > 0; off >>= 1) acc += __shfl_down(acc, off, 64);
  if (lane == 0) atomicAdd(&bsum, acc);
  __syncthreads();
  if (tid == 0) atomicAdd(Rsum, bsum);
}

__global__ void k_final(const float* __restrict__ Zloss,
                        const float* __restrict__ Rsum, float* __restrict__ out)
{
  // C_loss == Z_loss in forward (stop_gradient is identity forward)
  out[0] = 2.f * Zloss[0] + sqrtf(Rsum[0]);
}

// ---------------------------------------------------------------------------
// Workspace layout (bytes):
//   0         H1 bf16            [N*128]      33,554,432
//   33554432  topics int32       [N]             524,288
//   34078720  accumulators (zeroed by k_prep, 4 KB)
//   34082816  scale1[128]+shift1[128]
//   34083840  cn[512]
//   34085888  T[512*128] f32                   262,144
//   34348032  scale2[128]+shift2[128]
//   34349056  U[512*512] f32                 1,048,576   (W1t bf16 aliases; disjoint lifetime)
//   35397632  W2t bf16 [32][128]                 8,192
//   35405824  CBb bf16 [512][32]                32,768
// ---------------------------------------------------------------------------
extern "C" void kernel_launch(void* const* d_in, const int* in_sizes, int n_in,
                              void* d_out, int out_size, void* d_ws, size_t ws_size,
                              hipStream_t stream) {
  const float* X    = (const float*)d_in[0];
  const float* eW1  = (const float*)d_in[1];
  const float* eb1  = (const float*)d_in[2];
  const float* eg1  = (const float*)d_in[3];
  const float* ebe1 = (const float*)d_in[4];
  const float* eW2  = (const float*)d_in[5];
  const float* eb2  = (const float*)d_in[6];
  const float* CB   = (const float*)d_in[7];
  const float* dW1  = (const float*)d_in[8];
  const float* db1  = (const float*)d_in[9];
  const float* dg1  = (const float*)d_in[10];
  const float* dbe1 = (const float*)d_in[11];
  const float* dW2  = (const float*)d_in[12];
  const float* db2  = (const float*)d_in[13];
  float* out = (float*)d_out;

  char* wsb = (char*)d_ws;
  ushort_t* H1    = (ushort_t*)wsb;
  int* topics     = (int*)(wsb + 33554432);
  float* colsum   = (float*)(wsb + 34078720);
  float* colsumsq = colsum + 128;
  int* counts     = (int*)(wsb + 34078720 + 1024);
  float* Zloss    = (float*)(wsb + 34078720 + 3072);
  float* Rsum     = Zloss + 1;
  float* scale1   = (float*)(wsb + 34082816);
  float* shift1   = scale1 + 128;
  float* cn       = (float*)(wsb + 34083840);
  float* T        = (float*)(wsb + 34085888);
  float* scale2   = (float*)(wsb + 34348032);
  float* shift2   = scale2 + 128;
  float* U        = (float*)(wsb + 34349056);
  ushort_t* W1t   = (ushort_t*)(wsb + 34349056);  // aliases U (disjoint lifetime)
  ushort_t* W2t   = (ushort_t*)(wsb + 35397632);
  ushort_t* CBb   = (ushort_t*)(wsb + 35405824);

  k_prep<<<256, 256, 0, stream>>>(eW1, eW2, CB, W1t, W2t, CBb, cn, colsum);
  k_gemm1<<<NROWS / 128, 256, 0, stream>>>(X, W1t, eb1, H1, colsum, colsumsq);
  k_bn1<<<1, 128, 0, stream>>>(colsum, colsumsq, eg1, ebe1, scale1, shift1);
  k_encode<<<NROWS / 64, 256, 0, stream>>>(H1, scale1, shift1, W2t, eb2, CBb, cn,
                                           topics, counts, Zloss);
  k_T<<<KCODES * HDIM / 256, 256, 0, stream>>>(CB, dW1, db1, T);
  k_bn2<<<1, 128, 0, stream>>>(counts, T, dg1, dbe1, scale2, shift2);
  k_U<<<KCODES * 2, 256, 0, stream>>>(T, scale2, shift2, dW2, db2, U);
  k_recon<<<1024, 256, 0, stream>>>(X, U, topics, Rsum);
  k_final<<<1, 1, 0, stream>>>(Zloss, Rsum, out);
}